// Round 8
// baseline (154.156 us; speedup 1.0000x reference)
//
#include <hip/hip_runtime.h>
#include <hip/hip_bf16.h>

typedef unsigned short u16;
typedef __attribute__((ext_vector_type(8))) short short8;
typedef __attribute__((ext_vector_type(4))) short short4v;
typedef __attribute__((ext_vector_type(4))) float f32x4;

#define NB 8
#define TT 1024
#define DD 512
#define UU 512
#define HH 8
#define DH 64
#define SCALE 0.044194173824159216f   // 1/sqrt(512)
#define LOG2E 1.4426950408889634f
#define MASK_FILL_2 -1442695.0f       // -1e6 * log2e (exp2 domain)

__device__ __forceinline__ float ld_flex(const void* p, long i, bool f32) {
  if (f32) return ((const float*)p)[i];
  unsigned int u = (unsigned int)(((const u16*)p)[i]) << 16;
  return __uint_as_float(u);
}

__device__ __forceinline__ u16 f32_to_bf16(float f) {
  unsigned int u = __float_as_uint(f);
  unsigned int r = (u + 0x7FFFu + ((u >> 16) & 1u)) >> 16;  // RNE
  return (u16)r;
}

__device__ __forceinline__ float ex2(float x) {
#if __has_builtin(__builtin_amdgcn_exp2f)
  return __builtin_amdgcn_exp2f(x);
#else
  return __expf(x * 0.6931471805599453f);
#endif
}

__device__ __forceinline__ unsigned int pk_bf16(float a, float b) {
  union { __hip_bfloat162 h2; unsigned int u; } c;
  c.h2 = __float22bfloat162_rn(make_float2(a, b));
  return c.u;
}

// async 16B global -> LDS (wave-uniform LDS base + lane*16; global src per-lane)
__device__ __forceinline__ void gld16(const void* g, void* l) {
  __builtin_amdgcn_global_load_lds(
      (const __attribute__((address_space(1))) unsigned int*)g,
      (__attribute__((address_space(3))) unsigned int*)l, 16, 0, 0);
}

// ---------- merged prep: convert | wtrans | maskadd, with inline probing ----------
#define CONV_BLOCKS 2048
#define WT_BLOCKS 768
#define MASK_BLOCKS 32

__global__ __launch_bounds__(256) void prep_kernel(
    const void* __restrict__ query, const void* __restrict__ key,
    const void* __restrict__ W0, const void* __restrict__ W1,
    const void* __restrict__ W2, const void* __restrict__ mask,
    u16* __restrict__ Xq, u16* __restrict__ Xk, u16* __restrict__ Wt,
    float* __restrict__ maskadd, int* __restrict__ flags) {
  __shared__ float tile[32][33];
  __shared__ int s_f32, s_mi32;
  const int b = blockIdx.x, tid = threadIdx.x;

  // ---- inline probe (every block; 2 KB of query + 2 KB of mask, L2-hot) ----
  if (tid == 0) { s_f32 = 0; s_mi32 = 1; }
  __syncthreads();
  {
    const u16* qh = (const u16*)query;
    int weird = 0;
#pragma unroll
    for (int p = 0; p < 4; ++p) {
      unsigned int u = (unsigned int)qh[tid * 4 + p] << 16;
      float v = __uint_as_float(u);
      if (!(v == v) || fabsf(v) > 1e6f) weird = 1;
    }
    if (weird) atomicOr(&s_f32, 1);
    const unsigned int* mi = (const unsigned int*)mask;
    if (mi[tid * 2] > 1u || mi[tid * 2 + 1] > 1u) atomicAnd(&s_mi32, 0);
  }
  __syncthreads();
  const bool f32 = s_f32 != 0;
  const bool mi32 = s_mi32 != 0;
  if (b == CONV_BLOCKS && tid == 0) { flags[0] = s_f32; flags[1] = s_mi32; }

  if (b < CONV_BLOCKS) {
    if (!f32) return;  // bf16 in memory: proj reads query/key directly
    // grid-stride x4: 2048 blocks cover 2M float4 (query then key)
#pragma unroll
    for (int p = 0; p < 4; ++p) {
      const int i = b * 256 + tid + p * (CONV_BLOCKS * 256);
      const void* in = (i < 1048576) ? query : key;
      u16* outp = (i < 1048576) ? Xq : Xk;
      const int j = i & 1048575;
      float4 v = ((const float4*)in)[j];
      ushort4 o;
      o.x = f32_to_bf16(v.x); o.y = f32_to_bf16(v.y);
      o.z = f32_to_bf16(v.z); o.w = f32_to_bf16(v.w);
      ((ushort4*)outp)[j] = o;
    }
  } else if (b < CONV_BLOCKS + WT_BLOCKS) {
    const int lb = b - CONV_BLOCKS;
    const int z = lb >> 8, rem = lb & 255;
    const int k0 = (rem & 15) * 32, n0 = (rem >> 4) * 32;
    const void* W = (z == 0) ? W0 : (z == 1) ? W1 : W2;
    const float sc = (z == 0) ? SCALE * LOG2E : 1.0f;  // fold scale+log2e into Wq
    u16* out = Wt + (size_t)z * DD * UU;
#pragma unroll
    for (int p = 0; p < 4; ++p) {
      int i = (tid >> 5) + p * 8, j = tid & 31;
      tile[i][j] = ld_flex(W, (long)(k0 + i) * UU + n0 + j, f32);
    }
    __syncthreads();
#pragma unroll
    for (int p = 0; p < 4; ++p) {
      int nl = (tid >> 5) + p * 8, kl = tid & 31;
      out[(size_t)(n0 + nl) * DD + k0 + kl] = f32_to_bf16(tile[kl][nl] * sc);
    }
  } else {
    const int i = (b - CONV_BLOCKS - WT_BLOCKS) * 256 + tid;
    bool mv = mi32 ? (((const int*)mask)[i] != 0)
                   : (((const unsigned char*)mask)[i] != 0);
    maskadd[i] = mv ? 0.0f : MASK_FILL_2;
  }
}

// ---------- projection GEMM v3 (UNCHANGED — control): dbuf LDS, counted vmcnt ----------
__global__ __launch_bounds__(256) void proj_mfma(
    const void* __restrict__ query, const void* __restrict__ key,
    const u16* __restrict__ Xq, const u16* __restrict__ Xk,
    const u16* __restrict__ Wt, u16* __restrict__ Qp, u16* __restrict__ Kp,
    u16* __restrict__ Vt, const int* __restrict__ flags) {
  __shared__ __align__(16) u16 smem[128 * 136];
  const bool f32 = flags[0] != 0;
  const int lid = blockIdx.x + (blockIdx.y << 6) + (blockIdx.z << 8);
  const int swz = (lid & 7) * 96 + (lid >> 3);   // 768 % 8 == 0 -> bijective
  const int bx = swz & 63, by = (swz >> 6) & 3, z = swz >> 8;
  const u16* X = (z == 0) ? (f32 ? Xq : (const u16*)query)
                          : (f32 ? Xk : (const u16*)key);
  const u16* Wz = Wt + (size_t)z * DD * UU;
  const int m0 = bx * 128, n0 = by * 128;
  const int tid = threadIdx.x;
  const int w = tid >> 6, l = tid & 63;
  const int quad = l >> 4, l15 = l & 15;
  const int wm = (w >> 1) * 64, wn = (w & 1) * 64;

  const int c0 = w * 128 + l;
  const int row0 = c0 >> 2, q0 = (c0 & 3) * 8;
  const int c1 = c0 + 64;
  const int row1 = c1 >> 2, q1 = (c1 & 3) * 8;
  const u16* aS0 = X + (size_t)(m0 + row0) * DD + q0;
  const u16* aS1 = X + (size_t)(m0 + row1) * DD + q1;
  const u16* bS0 = Wz + (size_t)(n0 + row0) * DD + q0;
  const u16* bS1 = Wz + (size_t)(n0 + row1) * DD + q1;
  const int dD0 = w * 1024;
  const int dD1 = w * 1024 + 512;

  f32x4 acc[4][4];
#pragma unroll
  for (int mi = 0; mi < 4; ++mi)
#pragma unroll
    for (int ni = 0; ni < 4; ++ni)
#pragma unroll
      for (int r = 0; r < 4; ++r) acc[mi][ni][r] = 0.0f;

  gld16(aS0, smem + dD0);
  gld16(aS1, smem + dD1);
  gld16(bS0, smem + 4096 + dD0);
  gld16(bS1, smem + 4096 + dD1);

#pragma unroll 1
  for (int t = 0; t < 16; ++t) {
    const int co = (t & 1) * 8192;
    if (t < 15) {
      const int k1 = (t + 1) * 32;
      const int no = ((t + 1) & 1) * 8192;
      gld16(aS0 + k1, smem + no + dD0);
      gld16(aS1 + k1, smem + no + dD1);
      gld16(bS0 + k1, smem + no + 4096 + dD0);
      gld16(bS1 + k1, smem + no + 4096 + dD1);
      asm volatile("s_waitcnt vmcnt(4)" ::: "memory");
    } else {
      asm volatile("s_waitcnt vmcnt(0)" ::: "memory");
    }
    __builtin_amdgcn_s_barrier();

    short8 af[4], bf[4];
#pragma unroll
    for (int mi = 0; mi < 4; ++mi)
      af[mi] = *(const short8*)&smem[co + (wm + mi * 16 + l15) * 32 + quad * 8];
#pragma unroll
    for (int ni = 0; ni < 4; ++ni)
      bf[ni] = *(const short8*)&smem[co + 4096 + (wn + ni * 16 + l15) * 32 + quad * 8];
#pragma unroll
    for (int mi = 0; mi < 4; ++mi)
#pragma unroll
      for (int ni = 0; ni < 4; ++ni)
        acc[mi][ni] = __builtin_amdgcn_mfma_f32_16x16x32_bf16(
            af[mi], bf[ni], acc[mi][ni], 0, 0, 0);
    __builtin_amdgcn_s_barrier();
  }

  if (z < 2) {
#pragma unroll
    for (int mi = 0; mi < 4; ++mi)
#pragma unroll
      for (int ni = 0; ni < 4; ++ni) {
        const int ml = wm + mi * 16 + quad * 4;
        const int nl = wn + ni * 16 + l15;
#pragma unroll
        for (int r = 0; r < 4; ++r)
          smem[(ml + r) * 136 + nl] = f32_to_bf16(acc[mi][ni][r]);
      }
  } else {
#pragma unroll
    for (int mi = 0; mi < 4; ++mi)
#pragma unroll
      for (int ni = 0; ni < 4; ++ni) {
        const int ml = wm + mi * 16 + quad * 4;
        const int nl = wn + ni * 16 + l15;
        ushort4 pk;
        pk.x = f32_to_bf16(acc[mi][ni][0]);
        pk.y = f32_to_bf16(acc[mi][ni][1]);
        pk.z = f32_to_bf16(acc[mi][ni][2]);
        pk.w = f32_to_bf16(acc[mi][ni][3]);
        *(ushort4*)&smem[nl * 136 + ml] = pk;
      }
  }
  __syncthreads();

  if (z < 2) {
    u16* outp = (z == 0) ? Qp : Kp;
#pragma unroll
    for (int p = 0; p < 8; ++p) {
      const int idx = tid + p * 256;
      const int row = idx >> 4, c8 = (idx & 15) * 8;
      short8 v = *(const short8*)&smem[row * 136 + c8];
      *(short8*)&outp[(size_t)(m0 + row) * UU + n0 + c8] = v;
    }
  } else {
    const int nb = m0 >> 10, tk0 = m0 & 1023;
#pragma unroll
    for (int p = 0; p < 8; ++p) {
      const int idx = tid + p * 256;
      const int row = idx >> 4, c8 = (idx & 15) * 8;
      const int u = n0 + row, h = u >> 6, dh = u & 63;
      short8 v = *(const short8*)&smem[row * 136 + c8];
      *(short8*)&Vt[(size_t)((nb * HH + h) * DH + dh) * TT + tk0 + c8] = v;
    }
  }
}

// ---------- attention v7: 8 waves, 2-way k-split, 32 waves/CU ----------
// Grid (16,8,8)=1024 blocks x 512 thr -> 4 blocks/CU x 8 waves = 32 waves/CU
// (8/SIMD; v4-v6 were capped at 4/SIMD by the grid). Wave (qsub=w&3, ks=w>>2):
// 16 q-rows, k-window [ks*512, ks*512+512), KVBLK=32 staged dbuf per window
// (v4-verbatim addressing + ks base offsets), counted vmcnt(2). In-register P
// redistribution (v6). k-split merged via LDS O-partials in dead staging area.
// LDS 34.5KB; __launch_bounds__(512,8) caps VGPR at 64 (v6 measured 52).
__global__ __launch_bounds__(512, 8) void attn_mfma(
    const u16* __restrict__ Qp, const u16* __restrict__ Kp,
    const u16* __restrict__ Vt, const float* __restrict__ maskadd,
    void* __restrict__ out, const int* __restrict__ flags) {
  // LDS bytes: win0 K dbuf [0,8192) | win0 V dbuf [8192,16384)
  //            win1 K dbuf [16384,24576) | win1 V dbuf [24576,32768)
  //            mask bf16[1024] [32768,34816) | lp f32[128] [34816,35328)
  // epilogue: O-partials (16KB) reuse [0,16384)
  __shared__ __align__(16) char smem[35328];
  u16* sU = (u16*)smem;
  const int tid = threadIdx.x;
  const int w = tid >> 6, l = tid & 63;
  const int quad = l >> 4, l15 = l & 15;
  const int qsub = w & 3, ks = w >> 2;
  const int lid = blockIdx.x + (blockIdx.y << 4) + (blockIdx.z << 7);
  const int swz = (lid & 7) * 128 + (lid >> 3);   // batch n -> XCD n
  const int qt = swz & 15, h = (swz >> 4) & 7, n = swz >> 7;
  const int q0 = qt * 64;
  const bool f32o = flags[0] != 0;
  u16* s_mask = sU + 16384;           // u16 index (byte 32768)
  float* lp = (float*)(smem + 34816);

  // stage mask row as bf16 (values 0 / -1.44e6; bf16 rounding immaterial)
  if (tid < 256) {
    float4 m4 = ((const float4*)(maskadd + n * TT))[tid];
    ushort4 mu;
    mu.x = f32_to_bf16(m4.x); mu.y = f32_to_bf16(m4.y);
    mu.z = f32_to_bf16(m4.z); mu.w = f32_to_bf16(m4.w);
    ((ushort4*)s_mask)[tid] = mu;
  }

  // Q as B-frags: q = q0 + qsub*16 + l15, d = kd*32 + quad*8 + j
  const u16* qbase = Qp + (size_t)(n * TT + q0 + qsub * 16 + l15) * UU + h * DH + quad * 8;
  short8 bq[2];
  bq[0] = *(const short8*)(qbase);
  bq[1] = *(const short8*)(qbase + 32);

  // staging sources (v4 addressing + k-window): wave stages 8 K-rows and 16
  // V-rows of its window's tile; lane -> (row, phys slot); src col inverse-swz.
  const int lr3 = l >> 3, ls7 = l & 7;   // K: row qsub*8+lr3, slot ls7
  const int lr2 = l >> 2, ls3 = l & 3;   // V: row qsub*16+lr2, slot ls3
  const u16* kc = Kp + (size_t)(n * TT + ks * 512 + qsub * 8 + lr3) * UU + h * DH +
                  ((ls7 ^ lr3) * 8);
  const u16* vc = Vt + (size_t)((n * HH + h) * DH + qsub * 16 + lr2) * TT + ks * 512 +
                  ((ls3 ^ (lr2 & 3)) * 8);

  // window LDS bases (bytes)
  const int winb = ks * 16384;

  // P-shuffle source lanes (fixed permutation, v6-verified)
  const int srcA = ((quad & 1) << 5) + l15;
  const int srcB = srcA + 16;
  const bool hiK = (quad >> 1) != 0;

  f32x4 o[4];
  float lsum = 0.0f;
#pragma unroll
  for (int ni = 0; ni < 4; ++ni)
#pragma unroll
    for (int r = 0; r < 4; ++r) o[ni][r] = 0.0f;

  __syncthreads();  // s_mask visible (before any DMA is issued)

  // prologue: stage tile 0 of this window into buf 0
  gld16(kc, smem + winb + qsub * 1024);
  gld16(vc, smem + winb + 8192 + qsub * 1024);

#pragma unroll 1
  for (int t = 0; t < 16; ++t) {
    const int cu = (winb >> 1) + (t & 1) * 2048;  // u16 idx of current K buf
    if (t < 15) {
      const int nob = winb + ((t + 1) & 1) * 4096;  // byte offset of next buf
      gld16(kc + (size_t)(t + 1) * 32 * UU, smem + nob + qsub * 1024);
      gld16(vc + (t + 1) * 32, smem + nob + 8192 + qsub * 1024);
      // oldest 2 outstanding = stage(t); stage(t+1) stays in flight
      asm volatile("s_waitcnt vmcnt(2)" ::: "memory");
    } else {
      asm volatile("s_waitcnt vmcnt(0)" ::: "memory");
    }
    __builtin_amdgcn_s_barrier();   // tile t fully staged (all waves)

    const int kb = ks * 512 + t * 32;
    // K frags: row r = ktl*16+l15, slot = (kd*4+quad)^(r&7)
    short8 ak[2][2];
#pragma unroll
    for (int ktl = 0; ktl < 2; ++ktl)
#pragma unroll
      for (int kd = 0; kd < 2; ++kd)
        ak[ktl][kd] = *(const short8*)&sU[cu + (ktl * 16 + l15) * 64 +
                                          (((kd * 4 + quad) ^ (l15 & 7)) * 8)];

    // S = K . Q^T  (rows=k, cols=q)
    f32x4 s[2];
    __builtin_amdgcn_s_setprio(1);
#pragma unroll
    for (int ktl = 0; ktl < 2; ++ktl) {
#pragma unroll
      for (int r = 0; r < 4; ++r) s[ktl][r] = 0.0f;
#pragma unroll
      for (int kd = 0; kd < 2; ++kd)
        s[ktl] = __builtin_amdgcn_mfma_f32_16x16x32_bf16(
            ak[ktl][kd], bq[kd], s[ktl], 0, 0, 0);
    }
    __builtin_amdgcn_s_setprio(0);

    // exp2-domain softmax numerator, packed to bf16 dwords in-register
    unsigned int u00, u01, u10, u11;
    {
      ushort4 m0u = *(const ushort4*)&s_mask[kb + quad * 4];
      ushort4 m1u = *(const ushort4*)&s_mask[kb + 16 + quad * 4];
      float e0 = ex2(s[0][0] + __uint_as_float((unsigned)m0u.x << 16));
      float e1 = ex2(s[0][1] + __uint_as_float((unsigned)m0u.y << 16));
      float e2 = ex2(s[0][2] + __uint_as_float((unsigned)m0u.z << 16));
      float e3 = ex2(s[0][3] + __uint_as_float((unsigned)m0u.w << 16));
      float f0 = ex2(s[1][0] + __uint_as_float((unsigned)m1u.x << 16));
      float f1 = ex2(s[1][1] + __uint_as_float((unsigned)m1u.y << 16));
      float f2 = ex2(s[1][2] + __uint_as_float((unsigned)m1u.z << 16));
      float f3 = ex2(s[1][3] + __uint_as_float((unsigned)m1u.w << 16));
      lsum += ((e0 + e1) + (e2 + e3)) + ((f0 + f1) + (f2 + f3));
      u00 = pk_bf16(e0, e1); u01 = pk_bf16(e2, e3);
      u10 = pk_bf16(f0, f1); u11 = pk_bf16(f2, f3);
    }

    // in-register P redistribution: 8 shfl + 4 selects -> A-frag (v6-verified)
    short8 ap;
    {
      unsigned int a0k0 = __shfl(u00, srcA), a0k1 = __shfl(u10, srcA);
      unsigned int a1k0 = __shfl(u01, srcA), a1k1 = __shfl(u11, srcA);
      unsigned int a2k0 = __shfl(u00, srcB), a2k1 = __shfl(u10, srcB);
      unsigned int a3k0 = __shfl(u01, srcB), a3k1 = __shfl(u11, srcB);
      union { unsigned int d[4]; short8 v; } pu;
      pu.d[0] = hiK ? a0k1 : a0k0;
      pu.d[1] = hiK ? a1k1 : a1k0;
      pu.d[2] = hiK ? a2k1 : a2k0;
      pu.d[3] = hiK ? a3k1 : a3k0;
      ap = pu.v;
    }

    // V frags: row dh = ni*16+l15, slot = quad^(row&3)
    short8 vf[4];
#pragma unroll
    for (int ni = 0; ni < 4; ++ni)
      vf[ni] = *(const short8*)&sU[cu + 4096 + (ni * 16 + l15) * 32 +
                                   ((quad ^ (l15 & 3)) * 8)];

    // PV
    __builtin_amdgcn_s_setprio(1);
#pragma unroll
    for (int ni = 0; ni < 4; ++ni)
      o[ni] = __builtin_amdgcn_mfma_f32_16x16x32_bf16(ap, vf[ni], o[ni], 0, 0, 0);
    __builtin_amdgcn_s_setprio(0);

    __builtin_amdgcn_s_barrier();   // tile-t reads done before next DMA issue
  }

  // per-wave row sums over this k-window: butterfly across quads
  lsum += __shfl_xor(lsum, 16);
  lsum += __shfl_xor(lsum, 32);
  if (l < 16) lp[w * 16 + l] = lsum;

  // k-split merge: ks=1 waves publish O-partials into dead staging LDS
  __syncthreads();   // also protects staging area reuse (loop fully done)
  if (ks == 1) {
    float* Ost = (float*)smem + qsub * 1024;  // [16 q][64 dh] f32, 4KB
#pragma unroll
    for (int ni = 0; ni < 4; ++ni)
#pragma unroll
      for (int r = 0; r < 4; ++r)
        Ost[(quad * 4 + r) * 64 + ni * 16 + l15] = o[ni][r];
  }
  __syncthreads();

  if (ks == 0) {
    float* Ost = (float*)smem + qsub * 1024;
    float den[4];
#pragma unroll
    for (int r = 0; r < 4; ++r)
      den[r] = lp[w * 16 + quad * 4 + r] + lp[(w + 4) * 16 + quad * 4 + r];
#pragma unroll
    for (int ni = 0; ni < 4; ++ni)
#pragma unroll
      for (int r = 0; r < 4; ++r) {
        const int q = q0 + qsub * 16 + quad * 4 + r;
        const float v = (o[ni][r] + Ost[(quad * 4 + r) * 64 + ni * 16 + l15]) / den[r];
        const size_t idx = (size_t)(n * TT + q) * UU + h * DH + ni * 16 + l15;
        if (f32o) ((float*)out)[idx] = v;
        else ((u16*)out)[idx] = f32_to_bf16(v);
      }
  }
}

// ---------- launcher ----------
extern "C" void kernel_launch(void* const* d_in, const int* in_sizes, int n_in,
                              void* d_out, int out_size, void* d_ws, size_t ws_size,
                              hipStream_t stream) {
  const void* query = d_in[0];
  const void* key   = d_in[1];
  const void* mask  = d_in[2];
  const void* Wq    = d_in[3];
  const void* Wk    = d_in[4];
  const void* Wv    = d_in[5];

  char* base = (char*)d_ws;
  int* flags = (int*)base;
  float* maskadd = (float*)(base + 256);                  // 32 KB
  u16* Wt  = (u16*)(base + 64 * 1024);                    // 1.5 MB
  u16* Xq  = Wt + (size_t)3 * DD * UU;                    // 8 MB
  u16* Xk  = Xq + (size_t)NB * TT * DD;                   // 8 MB
  u16* Qp  = Xk + (size_t)NB * TT * DD;                   // 8 MB
  u16* Kp  = Qp + (size_t)NB * TT * UU;                   // 8 MB
  u16* Vtp = Kp + (size_t)NB * TT * UU;                   // 8 MB

  prep_kernel<<<CONV_BLOCKS + WT_BLOCKS + MASK_BLOCKS, 256, 0, stream>>>(
      query, key, Wq, Wk, Wv, mask, Xq, Xk, Wt, maskadd, flags);

  dim3 pgrid(NB * TT / 128, UU / 128, 3);  // (64, 4, 3)
  proj_mfma<<<pgrid, 256, 0, stream>>>(query, key, Xq, Xk, Wt, Qp, Kp, Vtp, flags);

  dim3 agrid(TT / 64, HH, NB);  // (16, 8, 8) -> 1024 blocks x 8 waves, 32 waves/CU
  attn_mfma<<<agrid, 512, 0, stream>>>(Qp, Kp, Vtp, maskadd, d_out, flags);
}

// Round 9
// 149.220 us; speedup vs baseline: 1.0331x; 1.0331x over previous
//
#include <hip/hip_runtime.h>
#include <hip/hip_bf16.h>

typedef unsigned short u16;
typedef __attribute__((ext_vector_type(8))) short short8;
typedef __attribute__((ext_vector_type(4))) short short4v;
typedef __attribute__((ext_vector_type(4))) float f32x4;

#define NB 8
#define TT 1024
#define DD 512
#define UU 512
#define HH 8
#define DH 64
#define SCALE 0.044194173824159216f   // 1/sqrt(512)
#define LOG2E 1.4426950408889634f
#define MASK_FILL_2 -1442695.0f       // -1e6 * log2e (exp2 domain)

__device__ __forceinline__ float ld_flex(const void* p, long i, bool f32) {
  if (f32) return ((const float*)p)[i];
  unsigned int u = (unsigned int)(((const u16*)p)[i]) << 16;
  return __uint_as_float(u);
}

__device__ __forceinline__ u16 f32_to_bf16(float f) {
  unsigned int u = __float_as_uint(f);
  unsigned int r = (u + 0x7FFFu + ((u >> 16) & 1u)) >> 16;  // RNE
  return (u16)r;
}

__device__ __forceinline__ float ex2(float x) {
#if __has_builtin(__builtin_amdgcn_exp2f)
  return __builtin_amdgcn_exp2f(x);
#else
  return __expf(x * 0.6931471805599453f);
#endif
}

__device__ __forceinline__ unsigned int pk_bf16(float a, float b) {
  union { __hip_bfloat162 h2; unsigned int u; } c;
  c.h2 = __float22bfloat162_rn(make_float2(a, b));
  return c.u;
}

// async 16B global -> LDS (wave-uniform LDS base + lane*16; global src per-lane)
__device__ __forceinline__ void gld16(const void* g, void* l) {
  __builtin_amdgcn_global_load_lds(
      (const __attribute__((address_space(1))) unsigned int*)g,
      (__attribute__((address_space(3))) unsigned int*)l, 16, 0, 0);
}

// ---------- merged prep: convert | wtrans | maskadd, with inline probing ----------
#define CONV_BLOCKS 8192
#define WT_BLOCKS 768
#define MASK_BLOCKS 32

__global__ __launch_bounds__(256) void prep_kernel(
    const void* __restrict__ query, const void* __restrict__ key,
    const void* __restrict__ W0, const void* __restrict__ W1,
    const void* __restrict__ W2, const void* __restrict__ mask,
    u16* __restrict__ Xq, u16* __restrict__ Xk, u16* __restrict__ Wt,
    float* __restrict__ maskadd, int* __restrict__ flags) {
  __shared__ float tile[32][33];
  __shared__ int s_f32, s_mi32;
  const int b = blockIdx.x, tid = threadIdx.x;

  // ---- inline probe (every block; 2 KB of query + 2 KB of mask, L2-hot) ----
  if (tid == 0) { s_f32 = 0; s_mi32 = 1; }
  __syncthreads();
  {
    const u16* qh = (const u16*)query;
    int weird = 0;
#pragma unroll
    for (int p = 0; p < 4; ++p) {
      unsigned int u = (unsigned int)qh[tid * 4 + p] << 16;
      float v = __uint_as_float(u);
      if (!(v == v) || fabsf(v) > 1e6f) weird = 1;
    }
    if (weird) atomicOr(&s_f32, 1);
    const unsigned int* mi = (const unsigned int*)mask;
    if (mi[tid * 2] > 1u || mi[tid * 2 + 1] > 1u) atomicAnd(&s_mi32, 0);
  }
  __syncthreads();
  const bool f32 = s_f32 != 0;
  const bool mi32 = s_mi32 != 0;
  if (b == CONV_BLOCKS && tid == 0) { flags[0] = s_f32; flags[1] = s_mi32; }

  if (b < CONV_BLOCKS) {
    if (!f32) return;  // bf16 in memory: proj reads query/key directly
    const void* in = (b < 4096) ? query : key;
    u16* out = (b < 4096) ? Xq : Xk;
    int i = (b & 4095) * 256 + tid;
    float4 v = ((const float4*)in)[i];
    ushort4 o;
    o.x = f32_to_bf16(v.x); o.y = f32_to_bf16(v.y);
    o.z = f32_to_bf16(v.z); o.w = f32_to_bf16(v.w);
    ((ushort4*)out)[i] = o;
  } else if (b < CONV_BLOCKS + WT_BLOCKS) {
    const int lb = b - CONV_BLOCKS;
    const int z = lb >> 8, rem = lb & 255;
    const int k0 = (rem & 15) * 32, n0 = (rem >> 4) * 32;
    const void* W = (z == 0) ? W0 : (z == 1) ? W1 : W2;
    const float sc = (z == 0) ? SCALE * LOG2E : 1.0f;  // fold scale+log2e into Wq
    u16* out = Wt + (size_t)z * DD * UU;
#pragma unroll
    for (int p = 0; p < 4; ++p) {
      int i = (tid >> 5) + p * 8, j = tid & 31;
      tile[i][j] = ld_flex(W, (long)(k0 + i) * UU + n0 + j, f32);
    }
    __syncthreads();
#pragma unroll
    for (int p = 0; p < 4; ++p) {
      int nl = (tid >> 5) + p * 8, kl = tid & 31;
      out[(size_t)(n0 + nl) * DD + k0 + kl] = f32_to_bf16(tile[kl][nl] * sc);
    }
  } else {
    const int i = (b - CONV_BLOCKS - WT_BLOCKS) * 256 + tid;
    bool mv = mi32 ? (((const int*)mask)[i] != 0)
                   : (((const unsigned char*)mask)[i] != 0);
    maskadd[i] = mv ? 0.0f : MASK_FILL_2;
  }
}

// ---------- projection GEMM v3: dbuf LDS staging, counted vmcnt ----------
__global__ __launch_bounds__(256) void proj_mfma(
    const void* __restrict__ query, const void* __restrict__ key,
    const u16* __restrict__ Xq, const u16* __restrict__ Xk,
    const u16* __restrict__ Wt, u16* __restrict__ Qp, u16* __restrict__ Kp,
    u16* __restrict__ Vt, const int* __restrict__ flags) {
  __shared__ __align__(16) u16 smem[128 * 136];
  const bool f32 = flags[0] != 0;
  const int lid = blockIdx.x + (blockIdx.y << 6) + (blockIdx.z << 8);
  const int swz = (lid & 7) * 96 + (lid >> 3);   // 768 % 8 == 0 -> bijective
  const int bx = swz & 63, by = (swz >> 6) & 3, z = swz >> 8;
  const u16* X = (z == 0) ? (f32 ? Xq : (const u16*)query)
                          : (f32 ? Xk : (const u16*)key);
  const u16* Wz = Wt + (size_t)z * DD * UU;
  const int m0 = bx * 128, n0 = by * 128;
  const int tid = threadIdx.x;
  const int w = tid >> 6, l = tid & 63;
  const int quad = l >> 4, l15 = l & 15;
  const int wm = (w >> 1) * 64, wn = (w & 1) * 64;

  const int c0 = w * 128 + l;
  const int row0 = c0 >> 2, q0 = (c0 & 3) * 8;
  const int c1 = c0 + 64;
  const int row1 = c1 >> 2, q1 = (c1 & 3) * 8;
  const u16* aS0 = X + (size_t)(m0 + row0) * DD + q0;
  const u16* aS1 = X + (size_t)(m0 + row1) * DD + q1;
  const u16* bS0 = Wz + (size_t)(n0 + row0) * DD + q0;
  const u16* bS1 = Wz + (size_t)(n0 + row1) * DD + q1;
  const int dD0 = w * 1024;
  const int dD1 = w * 1024 + 512;

  f32x4 acc[4][4];
#pragma unroll
  for (int mi = 0; mi < 4; ++mi)
#pragma unroll
    for (int ni = 0; ni < 4; ++ni)
#pragma unroll
      for (int r = 0; r < 4; ++r) acc[mi][ni][r] = 0.0f;

  gld16(aS0, smem + dD0);
  gld16(aS1, smem + dD1);
  gld16(bS0, smem + 4096 + dD0);
  gld16(bS1, smem + 4096 + dD1);

#pragma unroll 1
  for (int t = 0; t < 16; ++t) {
    const int co = (t & 1) * 8192;
    if (t < 15) {
      const int k1 = (t + 1) * 32;
      const int no = ((t + 1) & 1) * 8192;
      gld16(aS0 + k1, smem + no + dD0);
      gld16(aS1 + k1, smem + no + dD1);
      gld16(bS0 + k1, smem + no + 4096 + dD0);
      gld16(bS1 + k1, smem + no + 4096 + dD1);
      asm volatile("s_waitcnt vmcnt(4)" ::: "memory");
    } else {
      asm volatile("s_waitcnt vmcnt(0)" ::: "memory");
    }
    __builtin_amdgcn_s_barrier();

    short8 af[4], bf[4];
#pragma unroll
    for (int mi = 0; mi < 4; ++mi)
      af[mi] = *(const short8*)&smem[co + (wm + mi * 16 + l15) * 32 + quad * 8];
#pragma unroll
    for (int ni = 0; ni < 4; ++ni)
      bf[ni] = *(const short8*)&smem[co + 4096 + (wn + ni * 16 + l15) * 32 + quad * 8];
#pragma unroll
    for (int mi = 0; mi < 4; ++mi)
#pragma unroll
      for (int ni = 0; ni < 4; ++ni)
        acc[mi][ni] = __builtin_amdgcn_mfma_f32_16x16x32_bf16(
            af[mi], bf[ni], acc[mi][ni], 0, 0, 0);
    __builtin_amdgcn_s_barrier();
  }

  if (z < 2) {
#pragma unroll
    for (int mi = 0; mi < 4; ++mi)
#pragma unroll
      for (int ni = 0; ni < 4; ++ni) {
        const int ml = wm + mi * 16 + quad * 4;
        const int nl = wn + ni * 16 + l15;
#pragma unroll
        for (int r = 0; r < 4; ++r)
          smem[(ml + r) * 136 + nl] = f32_to_bf16(acc[mi][ni][r]);
      }
  } else {
#pragma unroll
    for (int mi = 0; mi < 4; ++mi)
#pragma unroll
      for (int ni = 0; ni < 4; ++ni) {
        const int ml = wm + mi * 16 + quad * 4;
        const int nl = wn + ni * 16 + l15;
        ushort4 pk;
        pk.x = f32_to_bf16(acc[mi][ni][0]);
        pk.y = f32_to_bf16(acc[mi][ni][1]);
        pk.z = f32_to_bf16(acc[mi][ni][2]);
        pk.w = f32_to_bf16(acc[mi][ni][3]);
        *(ushort4*)&smem[nl * 136 + ml] = pk;
      }
  }
  __syncthreads();

  if (z < 2) {
    u16* outp = (z == 0) ? Qp : Kp;
#pragma unroll
    for (int p = 0; p < 8; ++p) {
      const int idx = tid + p * 256;
      const int row = idx >> 4, c8 = (idx & 15) * 8;
      short8 v = *(const short8*)&smem[row * 136 + c8];
      *(short8*)&outp[(size_t)(m0 + row) * UU + n0 + c8] = v;
    }
  } else {
    const int nb = m0 >> 10, tk0 = m0 & 1023;
#pragma unroll
    for (int p = 0; p < 8; ++p) {
      const int idx = tid + p * 256;
      const int row = idx >> 4, c8 = (idx & 15) * 8;
      const int u = n0 + row, h = u >> 6, dh = u & 63;
      short8 v = *(const short8*)&smem[row * 136 + c8];
      *(short8*)&Vt[(size_t)((nb * HH + h) * DH + dh) * TT + tk0 + c8] = v;
    }
  }
}

// ---------- attention v4 (best measured: 150.5 µs total): DMA-staged K/V ----------
// 64 q-rows/block, 4 waves, wave w owns q-rows [qt*64+w*16, +16), full-k sweep.
// Per 32-k tile: K[32 k][64 d] (4KB) and V^T[64 d][32 k] (4KB) staged via
// global_load_lds, double-buffered; counted s_waitcnt vmcnt(2) keeps next
// tile's DMA in flight across compute; 2 raw barriers/iter.
// Rule-21 XOR swizzle: linear LDS dest + inverse-swizzled GLOBAL source +
// swizzled ds_read (K: slot^=(row&7); V: slot^=(row&3); slot=16B).
__global__ __launch_bounds__(256, 4) void attn_mfma(
    const u16* __restrict__ Qp, const u16* __restrict__ Kp,
    const u16* __restrict__ Vt, const float* __restrict__ maskadd,
    void* __restrict__ out, const int* __restrict__ flags) {
  // LDS bytes: K dbuf [0,8192) | V dbuf [8192,16384) | P 4x[16][36]u16
  // [16384,20992) | mask f32[1024] [20992,25088) | lp f32[64] [25088,25344)
  __shared__ __align__(16) char smem[25344];
  u16* sU = (u16*)smem;
  const int tid = threadIdx.x;
  const int w = tid >> 6, l = tid & 63;
  const int quad = l >> 4, l15 = l & 15;
  const int lid = blockIdx.x + (blockIdx.y << 4) + (blockIdx.z << 7);
  const int swz = (lid & 7) * 128 + (lid >> 3);   // batch n -> XCD n
  const int qt = swz & 15, h = (swz >> 4) & 7, n = swz >> 7;
  const int q0 = qt * 64;
  const bool f32o = flags[0] != 0;
  u16* Pw = sU + 8192 + w * 576;              // [16 q][36] u16, per-wave
  float* s_mask = (float*)(smem + 20992);
  float* lp = (float*)(smem + 25088);

  // stage mask row for this batch (plain LDS store, fenced by __syncthreads)
  ((float4*)s_mask)[tid] = ((const float4*)(maskadd + n * TT))[tid];

  // Q as B-frags: q = w*16 + l15, d = kd*32 + quad*8 + j
  const u16* qbase = Qp + (size_t)(n * TT + q0 + w * 16 + l15) * UU + h * DH + quad * 8;
  short8 bq[2];
  bq[0] = *(const short8*)(qbase);
  bq[1] = *(const short8*)(qbase + 32);

  // staging source addresses (per-lane, inverse-swizzled)
  const int lr3 = l >> 3, ls7 = l & 7;   // K: lane covers row w*8+lr3, phys slot ls7
  const int lr2 = l >> 2, ls3 = l & 3;   // V: lane covers row w*16+lr2, phys slot ls3
  const u16* kcur = Kp + (size_t)(n * TT + w * 8 + lr3) * UU + h * DH +
                    ((ls7 ^ lr3) * 8);
  const u16* vcur = Vt + (size_t)((n * HH + h) * DH + w * 16 + lr2) * TT +
                    ((ls3 ^ (lr2 & 3)) * 8);

  f32x4 o[4];
  float lsum = 0.0f;
#pragma unroll
  for (int ni = 0; ni < 4; ++ni)
#pragma unroll
    for (int r = 0; r < 4; ++r) o[ni][r] = 0.0f;

  __syncthreads();  // s_mask visible (before any DMA is issued)

  // prologue: stage tile 0 into buf 0
  gld16(kcur, smem + w * 1024);
  gld16(vcur, smem + 8192 + w * 1024);

#pragma unroll 1
  for (int t = 0; t < 32; ++t) {
    const int co = (t & 1) * 2048;  // u16 offset of current K buf (V at +4096)
    if (t < 31) {
      const int no = ((t + 1) & 1) * 4096;  // byte offset of next buf
      gld16(kcur + (size_t)(t + 1) * 32 * UU, smem + no + w * 1024);
      gld16(vcur + (t + 1) * 32, smem + 8192 + no + w * 1024);
      // oldest 2 outstanding = stage(t); stage(t+1) stays in flight
      asm volatile("s_waitcnt vmcnt(2)" ::: "memory");
    } else {
      asm volatile("s_waitcnt vmcnt(0)" ::: "memory");
    }
    __builtin_amdgcn_s_barrier();   // tile t fully staged (all waves)

    const int kb = t * 32;
    // K frags: row r = kt*16+l15, slot = (kd*4+quad)^(r&7)
    short8 ak[2][2];
#pragma unroll
    for (int kt = 0; kt < 2; ++kt)
#pragma unroll
      for (int kd = 0; kd < 2; ++kd)
        ak[kt][kd] = *(const short8*)&sU[co + (kt * 16 + l15) * 64 +
                                         (((kd * 4 + quad) ^ (l15 & 7)) * 8)];
    float4 mk0 = *(const float4*)&s_mask[kb + quad * 4];
    float4 mk1 = *(const float4*)&s_mask[kb + 16 + quad * 4];

    // S = K . Q^T  (rows=k, cols=q)
    f32x4 s[2];
#pragma unroll
    for (int kt = 0; kt < 2; ++kt) {
#pragma unroll
      for (int r = 0; r < 4; ++r) s[kt][r] = 0.0f;
#pragma unroll
      for (int kd = 0; kd < 2; ++kd)
        s[kt] = __builtin_amdgcn_mfma_f32_16x16x32_bf16(
            ak[kt][kd], bq[kd], s[kt], 0, 0, 0);
    }

    // exp2-domain softmax numerator -> P (bf16) via per-wave LDS
#pragma unroll
    for (int kt = 0; kt < 2; ++kt) {
      const float4 mk = kt ? mk1 : mk0;
      float e0 = ex2(s[kt][0] + mk.x);
      float e1 = ex2(s[kt][1] + mk.y);
      float e2 = ex2(s[kt][2] + mk.z);
      float e3 = ex2(s[kt][3] + mk.w);
      lsum += (e0 + e1) + (e2 + e3);
      uint2 pk = make_uint2(pk_bf16(e0, e1), pk_bf16(e2, e3));
      *(uint2*)&Pw[l15 * 36 + kt * 16 + quad * 4] = pk;
    }

    // V frags: row dh = ni*16+l15, slot = quad^(row&3)
    short8 vf[4];
#pragma unroll
    for (int ni = 0; ni < 4; ++ni)
      vf[ni] = *(const short8*)&sU[4096 + co + (ni * 16 + l15) * 32 +
                                   ((quad ^ (l15 & 3)) * 8)];

    // P readback as A-frag (compiler orders after P write via lgkmcnt)
    short8 ap;
    {
      short4v lo = *(const short4v*)&Pw[l15 * 36 + quad * 8];
      short4v hi = *(const short4v*)&Pw[l15 * 36 + quad * 8 + 4];
      union { short8 v8; short4v v4[2]; } u;
      u.v4[0] = lo; u.v4[1] = hi;
      ap = u.v8;
    }

    // PV
#pragma unroll
    for (int ni = 0; ni < 4; ++ni)
      o[ni] = __builtin_amdgcn_mfma_f32_16x16x32_bf16(ap, vf[ni], o[ni], 0, 0, 0);

    __builtin_amdgcn_s_barrier();   // tile-t reads done before next DMA issue
  }

  // full-k row sums: butterfly across quads, publish per-wave
  lsum += __shfl_xor(lsum, 16);
  lsum += __shfl_xor(lsum, 32);
  if (l < 16) lp[w * 16 + l] = lsum;
  __syncthreads();

  float den[4];
#pragma unroll
  for (int r = 0; r < 4; ++r) den[r] = lp[w * 16 + quad * 4 + r];

#pragma unroll
  for (int ni = 0; ni < 4; ++ni)
#pragma unroll
    for (int r = 0; r < 4; ++r) {
      const int q = q0 + w * 16 + quad * 4 + r;
      const float v = o[ni][r] / den[r];
      const size_t idx = (size_t)(n * TT + q) * UU + h * DH + ni * 16 + l15;
      if (f32o) ((float*)out)[idx] = v;
      else ((u16*)out)[idx] = f32_to_bf16(v);
    }
}

// ---------- launcher ----------
extern "C" void kernel_launch(void* const* d_in, const int* in_sizes, int n_in,
                              void* d_out, int out_size, void* d_ws, size_t ws_size,
                              hipStream_t stream) {
  const void* query = d_in[0];
  const void* key   = d_in[1];
  const void* mask  = d_in[2];
  const void* Wq    = d_in[3];
  const void* Wk    = d_in[4];
  const void* Wv    = d_in[5];

  char* base = (char*)d_ws;
  int* flags = (int*)base;
  float* maskadd = (float*)(base + 256);                  // 32 KB
  u16* Wt  = (u16*)(base + 64 * 1024);                    // 1.5 MB
  u16* Xq  = Wt + (size_t)3 * DD * UU;                    // 8 MB
  u16* Xk  = Xq + (size_t)NB * TT * DD;                   // 8 MB
  u16* Qp  = Xk + (size_t)NB * TT * DD;                   // 8 MB
  u16* Kp  = Qp + (size_t)NB * TT * UU;                   // 8 MB
  u16* Vtp = Kp + (size_t)NB * TT * UU;                   // 8 MB

  prep_kernel<<<CONV_BLOCKS + WT_BLOCKS + MASK_BLOCKS, 256, 0, stream>>>(
      query, key, Wq, Wk, Wv, mask, Xq, Xk, Wt, maskadd, flags);

  dim3 pgrid(NB * TT / 128, UU / 128, 3);  // (64, 4, 3)
  proj_mfma<<<pgrid, 256, 0, stream>>>(query, key, Xq, Xk, Wt, Qp, Kp, Vtp, flags);

  dim3 agrid(TT / 64, HH, NB);  // (16, 8, 8) -> 1024 blocks, 4/CU
  attn_mfma<<<agrid, 256, 0, stream>>>(Qp, Kp, Vtp, maskadd, d_out, flags);
}